// Round 5
// baseline (277.927 us; speedup 1.0000x reference)
//
#include <hip/hip_runtime.h>

typedef float f32x4 __attribute__((ext_vector_type(4)));
typedef short s16x8 __attribute__((ext_vector_type(8)));
typedef short s16x4 __attribute__((ext_vector_type(4)));
typedef unsigned short u16;

#define N_COLS 4096
#define RANK 64

__device__ __forceinline__ unsigned f_asuint(float f) { union { float f; unsigned u; } v; v.f = f; return v.u; }
__device__ __forceinline__ float f_asfloat(unsigned u) { union { unsigned u; float f; } v; v.u = u; return v.f; }
// fp32 -> bf16 round-to-nearest-even
__device__ __forceinline__ short f2bf(float f) {
  unsigned u = f_asuint(f);
  return (short)((u + 0x7fffu + ((u >> 16) & 1u)) >> 16);
}

// async global->LDS, 16B per lane; LDS dest = wave-uniform base + lane*16
__device__ __forceinline__ void gload_lds16(const void* g, void* l) {
  __builtin_amdgcn_global_load_lds(
      (const __attribute__((address_space(1))) unsigned int*)g,
      (__attribute__((address_space(3))) unsigned int*)l,
      16, 0, 0);
}

// ---------------------------------------------------------------------------
// Kernel 0: W[r][n] = b_q[n/64][r] * c_q_t[r][n%64]  (bf16, [64][4096])
// (a_bf prep dropped -- k_gemm2 now converts a_q in-register.)
// ---------------------------------------------------------------------------
__global__ __launch_bounds__(256) void k_prep(const float* __restrict__ b_q,
                                              const float* __restrict__ c_q_t,
                                              u16* __restrict__ W) {
  int j = blockIdx.x * 256 + threadIdx.x;   // [0, 32768)
  int r = j >> 9;
  int n0 = (j << 3) & 4095;
  float b = b_q[(n0 >> 6) * RANK + r];
  const f32x4* cp = reinterpret_cast<const f32x4*>(c_q_t + (r << 6) + (n0 & 63));
  f32x4 c0 = cp[0], c1 = cp[1];
  s16x8 w;
  w[0] = f2bf(b * c0.x); w[1] = f2bf(b * c0.y); w[2] = f2bf(b * c0.z); w[3] = f2bf(b * c0.w);
  w[4] = f2bf(b * c1.x); w[5] = f2bf(b * c1.y); w[6] = f2bf(b * c1.z); w[7] = f2bf(b * c1.w);
  *reinterpret_cast<s16x8*>(W + ((size_t)j << 3)) = w;
}

// ---------------------------------------------------------------------------
// Kernel 1: quant(x*smooth) fused with partial h2 = xq @ W^T over a K-quarter.
// Grid (T/16, 4). 256 thr (4 waves). x staged to LDS via global_load_lds
// (double-buffered 16tok x 256col tiles; source col pre-swizzled so linear
// LDS reads back conflict-free). smooth staged once (broadcast reads).
// Partials (f32) -> h2p[kb][T][64]. (Unchanged from verified round-4 version.)
// ---------------------------------------------------------------------------
__global__ __launch_bounds__(256, 4) void k_h2(const float* __restrict__ x,
                                               const float* __restrict__ smooth,
                                               const u16* __restrict__ W,
                                               float* __restrict__ h2p,
                                               int T) {
  const int t0 = blockIdx.x * 16;
  const int kb = blockIdx.y;           // K-quarter 0..3
  const int wave = threadIdx.x >> 6;   // 0..3
  const int lane = threadIdx.x & 63;
  const int quad = lane >> 4;
  const int tl = lane & 15;
  const int K0b = kb << 10;

  __shared__ float xbuf[2][4096];      // 2 x 16 KB (16 tok x 256 col)
  __shared__ float sml[1024];          // 4 KB (this block's K-quarter of smooth)

  // ---- stage smooth (linear; reads are wave-broadcast -> conflict-free) ----
  gload_lds16(smooth + K0b + wave * 256 + (lane << 2), &sml[wave * 256]);

  // ---- x stage step 0: token q*4+wave, full 256-col row, 16B/lane.
  // Source col pre-swizzled (c = (lane*4) ^ ((tok&7)*4)) so LDS stays linear.
  const int colL = lane << 2;          // 0..252
#pragma unroll
  for (int q = 0; q < 4; ++q) {
    int tok = q * 4 + wave;
    int c = colL ^ ((tok & 7) << 2);
    gload_lds16(x + (size_t)(t0 + tok) * N_COLS + K0b + c, &xbuf[0][tok * 256]);
  }
  __syncthreads();                     // drain smooth + step-0 stage

  f32x4 acc0 = {0.f, 0.f, 0.f, 0.f};
  f32x4 acc1 = {0.f, 0.f, 0.f, 0.f};
  f32x4 acc2 = {0.f, 0.f, 0.f, 0.f};
  f32x4 acc3 = {0.f, 0.f, 0.f, 0.f};

  const int c0w = wave * 64 + quad * 8;
  const int swz = (tl & 7) << 2;
  const u16* wpB = W + (size_t)tl * N_COLS + K0b + c0w;

#pragma unroll
  for (int t = 0; t < 4; ++t) {
    // prefetch next x tile into the other buffer (drained at this step's barrier)
    if (t + 1 < 4) {
#pragma unroll
      for (int q = 0; q < 4; ++q) {
        int tok = q * 4 + wave;
        int c = colL ^ ((tok & 7) << 2);
        gload_lds16(x + (size_t)(t0 + tok) * N_COLS + K0b + (t + 1) * 256 + c,
                    &xbuf[(t + 1) & 1][tok * 256]);
      }
    }

    // W fragments for this step (L2-resident; latency hidden under quant VALU)
    s16x8 w8[2][4];
#pragma unroll
    for (int si = 0; si < 2; ++si)
#pragma unroll
      for (int i = 0; i < 4; ++i)
        w8[si][i] = *reinterpret_cast<const s16x8*>(
            wpB + t * 256 + si * 32 + (size_t)i * 16 * N_COLS);

    const float* xb = xbuf[t & 1];
#pragma unroll
    for (int si = 0; si < 2; ++si) {
      const int cs = c0w + si * 32;
      f32x4 xa = *reinterpret_cast<const f32x4*>(xb + tl * 256 + (cs ^ swz));
      f32x4 xv = *reinterpret_cast<const f32x4*>(xb + tl * 256 + ((cs + 4) ^ swz));
      f32x4 sa = *reinterpret_cast<const f32x4*>(sml + t * 256 + cs);
      f32x4 sb = *reinterpret_cast<const f32x4*>(sml + t * 256 + cs + 4);

      float xs[8];
      xs[0] = xa.x * sa.x; xs[1] = xa.y * sa.y; xs[2] = xa.z * sa.z; xs[3] = xa.w * sa.w;
      xs[4] = xv.x * sb.x; xs[5] = xv.y * sb.y; xs[6] = xv.z * sb.z; xs[7] = xv.w * sb.w;

      // amax over the 16-block: 8 local + partner half in lane^16 (same token)
      float amax = fabsf(xs[0]);
#pragma unroll
      for (int j = 1; j < 8; ++j) amax = fmaxf(amax, fabsf(xs[j]));
      amax = fmaxf(amax, __shfl_xor(amax, 16));
      float scale = fmaxf(amax * (1.0f / 6.0f), 1e-8f);

      // searchsorted(mids, |y|, 'right') == count(|x| >= mid*scale)
      const float th0 = 0.25f * scale, th1 = 0.75f * scale, th2 = 1.25f * scale,
                  th3 = 1.75f * scale, th4 = 2.5f * scale, th5 = 3.5f * scale,
                  th6 = 5.0f * scale;
      s16x8 af;
#pragma unroll
      for (int j = 0; j < 8; ++j) {
        float ax = fabsf(xs[j]);
        float q = (ax >= th0) ? 0.5f : 0.0f;
        q = (ax >= th1) ? 1.0f : q;
        q = (ax >= th2) ? 1.5f : q;
        q = (ax >= th3) ? 2.0f : q;
        q = (ax >= th4) ? 3.0f : q;
        q = (ax >= th5) ? 4.0f : q;
        q = (ax >= th6) ? 6.0f : q;
        float xq = q * scale;
        xq = f_asfloat(f_asuint(xq) | (f_asuint(xs[j]) & 0x80000000u));
        af[j] = f2bf(xq);
      }

      acc0 = __builtin_amdgcn_mfma_f32_16x16x32_bf16(af, w8[si][0], acc0, 0, 0, 0);
      acc1 = __builtin_amdgcn_mfma_f32_16x16x32_bf16(af, w8[si][1], acc1, 0, 0, 0);
      acc2 = __builtin_amdgcn_mfma_f32_16x16x32_bf16(af, w8[si][2], acc2, 0, 0, 0);
      acc3 = __builtin_amdgcn_mfma_f32_16x16x32_bf16(af, w8[si][3], acc3, 0, 0, 0);
    }
    __syncthreads();                   // drains next-tile stage, syncs buffers
  }

  // cross-wave reduction of 4 K-split partials -> f32 h2p.
  // red aliases xbuf[0] (all reads of xbuf are complete past the last barrier).
  float* red = &xbuf[0][0];
  float* rw = red + wave * 1024 + (quad * 4) * 64 + tl;
#pragma unroll
  for (int reg = 0; reg < 4; ++reg) {
    rw[reg * 64 + 0]  = acc0[reg];
    rw[reg * 64 + 16] = acc1[reg];
    rw[reg * 64 + 32] = acc2[reg];
    rw[reg * 64 + 48] = acc3[reg];
  }
  __syncthreads();
  {
    const f32x4* r4 = reinterpret_cast<const f32x4*>(red);
    f32x4 v = r4[threadIdx.x];
#pragma unroll
    for (int p = 1; p < 4; ++p) {
      f32x4 u = r4[p * 256 + threadIdx.x];
      v.x += u.x; v.y += u.y; v.z += u.z; v.w += u.w;
    }
    int t = threadIdx.x >> 4;          // token 0..15
    int rr = (threadIdx.x & 15) * 4;   // r offset
    *reinterpret_cast<f32x4*>(h2p + ((size_t)kb * T + t0 + t) * RANK + rr) = v;
  }
}

// ---------------------------------------------------------------------------
// Kernel 2: out[t][m] = bias[m] + h2[t][:] . bf16(a_q[m][:])   (K = 64)
// 64t x 256m tile (2048 blocks). Prologue sums 4 f32 K-partials -> bf16 h2 in
// LDS (stride 72 shorts = 144 B, 16B-aligned, naturally bank-staggered).
// A-fragments converted from a_q f32 in-register (bit-identical to prep'd
// a_bf). Epilogue: 4 chunked LDS transposes -> contiguous CACHED f32x4 stores
// (NT dropped -- suspect for the write-BW gap vs the 6.7 TB/s fill).
// ---------------------------------------------------------------------------
__global__ __launch_bounds__(256, 4) void k_gemm2(const float* __restrict__ h2p,
                                                  const float* __restrict__ a_q,
                                                  const float* __restrict__ bias,
                                                  float* __restrict__ out,
                                                  int T) {
  const int t0 = blockIdx.y * 64;
  const int m0 = blockIdx.x * 256;
  const int wave = threadIdx.x >> 6;
  const int lane = threadIdx.x & 63;
  const int quad = lane >> 4;
  const int tl = lane & 15;

  __shared__ u16 h2l[64 * 72];         // 9216 B
  __shared__ float tile[16 * 260];     // 16640 B

  // prologue: sum 4 K-partials for 64 tokens, cvt -> bf16 LDS
  {
    int t = threadIdx.x >> 2;            // token 0..63
    int r0 = (threadIdx.x & 3) * 16;     // r offset 0/16/32/48
    const float* p = h2p + (size_t)(t0 + t) * RANK + r0;
    f32x4 v0 = *reinterpret_cast<const f32x4*>(p);
    f32x4 v1 = *reinterpret_cast<const f32x4*>(p + 4);
    f32x4 v2 = *reinterpret_cast<const f32x4*>(p + 8);
    f32x4 v3 = *reinterpret_cast<const f32x4*>(p + 12);
#pragma unroll
    for (int kb = 1; kb < 4; ++kb) {
      const float* q = p + (size_t)kb * T * RANK;
      f32x4 u0 = *reinterpret_cast<const f32x4*>(q);
      f32x4 u1 = *reinterpret_cast<const f32x4*>(q + 4);
      f32x4 u2 = *reinterpret_cast<const f32x4*>(q + 8);
      f32x4 u3 = *reinterpret_cast<const f32x4*>(q + 12);
      v0.x += u0.x; v0.y += u0.y; v0.z += u0.z; v0.w += u0.w;
      v1.x += u1.x; v1.y += u1.y; v1.z += u1.z; v1.w += u1.w;
      v2.x += u2.x; v2.y += u2.y; v2.z += u2.z; v2.w += u2.w;
      v3.x += u3.x; v3.y += u3.y; v3.z += u3.z; v3.w += u3.w;
    }
    s16x8 h0, h1;
    h0[0] = f2bf(v0.x); h0[1] = f2bf(v0.y); h0[2] = f2bf(v0.z); h0[3] = f2bf(v0.w);
    h0[4] = f2bf(v1.x); h0[5] = f2bf(v1.y); h0[6] = f2bf(v1.z); h0[7] = f2bf(v1.w);
    h1[0] = f2bf(v2.x); h1[1] = f2bf(v2.y); h1[2] = f2bf(v2.z); h1[3] = f2bf(v2.w);
    h1[4] = f2bf(v3.x); h1[5] = f2bf(v3.y); h1[6] = f2bf(v3.z); h1[7] = f2bf(v3.w);
    *reinterpret_cast<s16x8*>(h2l + t * 72 + r0) = h0;
    *reinterpret_cast<s16x8*>(h2l + t * 72 + r0 + 8) = h1;
  }
  __syncthreads();

  // MFMA: 4 token-groups x 4 m-groups, A-frags from a_q (f32->bf16 in-reg)
  const float* aq = a_q + (size_t)(m0 + wave * 64 + tl) * RANK + quad * 8;

  f32x4 acc[4][4] = {};

#pragma unroll
  for (int o = 0; o < 64; o += 32) {
    s16x8 afr[4];
#pragma unroll
    for (int mg = 0; mg < 4; ++mg) {
      const float* aq2 = aq + (size_t)mg * 16 * RANK + o;
      f32x4 a0 = *reinterpret_cast<const f32x4*>(aq2);
      f32x4 a1 = *reinterpret_cast<const f32x4*>(aq2 + 4);
      afr[mg][0] = f2bf(a0.x); afr[mg][1] = f2bf(a0.y);
      afr[mg][2] = f2bf(a0.z); afr[mg][3] = f2bf(a0.w);
      afr[mg][4] = f2bf(a1.x); afr[mg][5] = f2bf(a1.y);
      afr[mg][6] = f2bf(a1.z); afr[mg][7] = f2bf(a1.w);
    }
#pragma unroll
    for (int tg = 0; tg < 4; ++tg) {
      s16x8 hfr = *reinterpret_cast<const s16x8*>(h2l + (tg * 16 + tl) * 72 + quad * 8 + o);
#pragma unroll
      for (int mg = 0; mg < 4; ++mg)
        acc[tg][mg] = __builtin_amdgcn_mfma_f32_16x16x32_bf16(hfr, afr[mg], acc[tg][mg], 0, 0, 0);
    }
  }

#pragma unroll
  for (int tg = 0; tg < 4; ++tg) {
    __syncthreads();                   // protect tile from previous tg's reads
#pragma unroll
    for (int mg = 0; mg < 4; ++mg)
#pragma unroll
      for (int reg = 0; reg < 4; ++reg)
        tile[(quad * 4 + reg) * 260 + wave * 64 + mg * 16 + tl] = acc[tg][mg][reg];
    __syncthreads();
#pragma unroll
    for (int i = 0; i < 4; ++i) {
      int idx = threadIdx.x + i * 256;   // 1024 float4 = 16 x 256 chunk
      int row = idx >> 6;
      int c4 = (idx & 63) << 2;
      f32x4 v = *reinterpret_cast<const f32x4*>(tile + row * 260 + c4);
      f32x4 b = *reinterpret_cast<const f32x4*>(bias + m0 + c4);
      f32x4 ov;
      ov.x = v.x + b.x; ov.y = v.y + b.y; ov.z = v.z + b.z; ov.w = v.w + b.w;
      *reinterpret_cast<f32x4*>(out + (size_t)(t0 + tg * 16 + row) * N_COLS + m0 + c4) = ov;
    }
  }
}

// ---------------------------------------------------------------------------
extern "C" void kernel_launch(void* const* d_in, const int* in_sizes, int n_in,
                              void* d_out, int out_size, void* d_ws, size_t ws_size,
                              hipStream_t stream) {
  const float* x      = (const float*)d_in[0];
  const float* smooth = (const float*)d_in[1];
  const float* a_q    = (const float*)d_in[2];
  const float* b_q    = (const float*)d_in[3];
  const float* c_q_t  = (const float*)d_in[4];
  const float* bias   = (const float*)d_in[5];
  float* out = (float*)d_out;

  const int T = in_sizes[0] / N_COLS;  // 8192 tokens

  u16* W     = (u16*)d_ws;                                  // 512 KB
  float* h2p = (float*)((char*)d_ws + 524288);              // 4*T*64*4 = 8 MB

  k_prep<<<128, 256, 0, stream>>>(b_q, c_q_t, W);
  dim3 gh(T / 16, 4);
  k_h2<<<gh, 256, 0, stream>>>(x, smooth, W, h2p, T);
  dim3 g2(N_COLS / 256, T / 64);
  k_gemm2<<<g2, 256, 0, stream>>>(h2p, a_q, bias, out, T);
}

// Round 6
// 262.779 us; speedup vs baseline: 1.0576x; 1.0576x over previous
//
#include <hip/hip_runtime.h>

typedef float f32x4 __attribute__((ext_vector_type(4)));
typedef short s16x8 __attribute__((ext_vector_type(8)));
typedef short s16x4 __attribute__((ext_vector_type(4)));
typedef unsigned short u16;

#define N_COLS 4096
#define RANK 64

__device__ __forceinline__ unsigned f_asuint(float f) { union { float f; unsigned u; } v; v.f = f; return v.u; }
__device__ __forceinline__ float f_asfloat(unsigned u) { union { unsigned u; float f; } v; v.u = u; return v.f; }
// fp32 -> bf16 round-to-nearest-even
__device__ __forceinline__ short f2bf(float f) {
  unsigned u = f_asuint(f);
  return (short)((u + 0x7fffu + ((u >> 16) & 1u)) >> 16);
}

// async global->LDS, 16B per lane; LDS dest = wave-uniform base + lane*16
__device__ __forceinline__ void gload_lds16(const void* g, void* l) {
  __builtin_amdgcn_global_load_lds(
      (const __attribute__((address_space(1))) unsigned int*)g,
      (__attribute__((address_space(3))) unsigned int*)l,
      16, 0, 0);
}

// ---------------------------------------------------------------------------
// Kernel 0 (8x vectorized): W[r][n] = b_q[n/64][r] * c_q_t[r][n%64]  (bf16)
//                           a_bf[m][r] = bf16(a_q[m][r])
// (exact round-4 version)
// ---------------------------------------------------------------------------
__global__ __launch_bounds__(256) void k_prep(const float* __restrict__ b_q,
                                              const float* __restrict__ c_q_t,
                                              const float* __restrict__ a_q,
                                              u16* __restrict__ W,
                                              u16* __restrict__ a_bf) {
  int j = blockIdx.x * 256 + threadIdx.x;   // [0, 65536)
  if (j < 32768) {
    int r = j >> 9;
    int n0 = (j << 3) & 4095;
    float b = b_q[(n0 >> 6) * RANK + r];
    const f32x4* cp = reinterpret_cast<const f32x4*>(c_q_t + (r << 6) + (n0 & 63));
    f32x4 c0 = cp[0], c1 = cp[1];
    s16x8 w;
    w[0] = f2bf(b * c0.x); w[1] = f2bf(b * c0.y); w[2] = f2bf(b * c0.z); w[3] = f2bf(b * c0.w);
    w[4] = f2bf(b * c1.x); w[5] = f2bf(b * c1.y); w[6] = f2bf(b * c1.z); w[7] = f2bf(b * c1.w);
    *reinterpret_cast<s16x8*>(W + ((size_t)j << 3)) = w;
  } else {
    int j2 = j - 32768;
    const f32x4* ap = reinterpret_cast<const f32x4*>(a_q + ((size_t)j2 << 3));
    f32x4 a0 = ap[0], a1 = ap[1];
    s16x8 v;
    v[0] = f2bf(a0.x); v[1] = f2bf(a0.y); v[2] = f2bf(a0.z); v[3] = f2bf(a0.w);
    v[4] = f2bf(a1.x); v[5] = f2bf(a1.y); v[6] = f2bf(a1.z); v[7] = f2bf(a1.w);
    *reinterpret_cast<s16x8*>(a_bf + ((size_t)j2 << 3)) = v;
  }
}

// ---------------------------------------------------------------------------
// Kernel 1: quant(x*smooth) fused with partial h2 = xq @ W^T over a K-HALF.
// Grid (T/16, 2). 256 thr (4 waves). x staged to LDS via global_load_lds
// (double-buffered 16tok x 256col tiles; source col pre-swizzled so linear
// LDS reads back conflict-free). smooth K-half staged once (broadcast reads).
// 8 steps per block (vs 4 in round 4): halves h2p traffic and amortizes
// prologue/epilogue. LDS = 32K xbuf + 8K sml = 40K -> exactly 4 blocks/CU.
// Partials (f32) -> h2p[kb][T][64].
// ---------------------------------------------------------------------------
__global__ __launch_bounds__(256, 4) void k_h2(const float* __restrict__ x,
                                               const float* __restrict__ smooth,
                                               const u16* __restrict__ W,
                                               float* __restrict__ h2p,
                                               int T) {
  const int t0 = blockIdx.x * 16;
  const int kb = blockIdx.y;           // K-half 0..1
  const int wave = threadIdx.x >> 6;   // 0..3
  const int lane = threadIdx.x & 63;
  const int quad = lane >> 4;
  const int tl = lane & 15;
  const int K0b = kb << 11;            // 0 or 2048

  __shared__ float xbuf[2][4096];      // 2 x 16 KB (16 tok x 256 col)
  __shared__ float sml[2048];          // 8 KB (this block's K-half of smooth)

  // ---- stage smooth (linear; reads are wave-broadcast -> conflict-free) ----
#pragma unroll
  for (int rr = 0; rr < 2; ++rr)
    gload_lds16(smooth + K0b + rr * 1024 + wave * 256 + (lane << 2),
                &sml[rr * 1024 + wave * 256]);

  // ---- x stage step 0: token q*4+wave, full 256-col row, 16B/lane.
  // Source col pre-swizzled (c = (lane*4) ^ ((tok&7)*4)) so LDS stays linear.
  const int colL = lane << 2;          // 0..252
#pragma unroll
  for (int q = 0; q < 4; ++q) {
    int tok = q * 4 + wave;
    int c = colL ^ ((tok & 7) << 2);
    gload_lds16(x + (size_t)(t0 + tok) * N_COLS + K0b + c, &xbuf[0][tok * 256]);
  }
  __syncthreads();                     // drain smooth + step-0 stage

  f32x4 acc0 = {0.f, 0.f, 0.f, 0.f};
  f32x4 acc1 = {0.f, 0.f, 0.f, 0.f};
  f32x4 acc2 = {0.f, 0.f, 0.f, 0.f};
  f32x4 acc3 = {0.f, 0.f, 0.f, 0.f};

  const int c0w = wave * 64 + quad * 8;
  const int swz = (tl & 7) << 2;
  const u16* wpB = W + (size_t)tl * N_COLS + K0b + c0w;

#pragma unroll
  for (int t = 0; t < 8; ++t) {
    // prefetch next x tile into the other buffer (drained at this step's barrier)
    if (t + 1 < 8) {
#pragma unroll
      for (int q = 0; q < 4; ++q) {
        int tok = q * 4 + wave;
        int c = colL ^ ((tok & 7) << 2);
        gload_lds16(x + (size_t)(t0 + tok) * N_COLS + K0b + (t + 1) * 256 + c,
                    &xbuf[(t + 1) & 1][tok * 256]);
      }
    }

    // W fragments for this step (L2-resident; latency hidden under quant VALU)
    s16x8 w8[2][4];
#pragma unroll
    for (int si = 0; si < 2; ++si)
#pragma unroll
      for (int i = 0; i < 4; ++i)
        w8[si][i] = *reinterpret_cast<const s16x8*>(
            wpB + t * 256 + si * 32 + (size_t)i * 16 * N_COLS);

    const float* xb = xbuf[t & 1];
#pragma unroll
    for (int si = 0; si < 2; ++si) {
      const int cs = c0w + si * 32;
      f32x4 xa = *reinterpret_cast<const f32x4*>(xb + tl * 256 + (cs ^ swz));
      f32x4 xv = *reinterpret_cast<const f32x4*>(xb + tl * 256 + ((cs + 4) ^ swz));
      f32x4 sa = *reinterpret_cast<const f32x4*>(sml + t * 256 + cs);
      f32x4 sb = *reinterpret_cast<const f32x4*>(sml + t * 256 + cs + 4);

      float xs[8];
      xs[0] = xa.x * sa.x; xs[1] = xa.y * sa.y; xs[2] = xa.z * sa.z; xs[3] = xa.w * sa.w;
      xs[4] = xv.x * sb.x; xs[5] = xv.y * sb.y; xs[6] = xv.z * sb.z; xs[7] = xv.w * sb.w;

      // amax over the 16-block: 8 local + partner half in lane^16 (same token)
      float amax = fabsf(xs[0]);
#pragma unroll
      for (int j = 1; j < 8; ++j) amax = fmaxf(amax, fabsf(xs[j]));
      amax = fmaxf(amax, __shfl_xor(amax, 16));
      float scale = fmaxf(amax * (1.0f / 6.0f), 1e-8f);

      // searchsorted(mids, |y|, 'right') == count(|x| >= mid*scale)
      const float th0 = 0.25f * scale, th1 = 0.75f * scale, th2 = 1.25f * scale,
                  th3 = 1.75f * scale, th4 = 2.5f * scale, th5 = 3.5f * scale,
                  th6 = 5.0f * scale;
      s16x8 af;
#pragma unroll
      for (int j = 0; j < 8; ++j) {
        float ax = fabsf(xs[j]);
        float q = (ax >= th0) ? 0.5f : 0.0f;
        q = (ax >= th1) ? 1.0f : q;
        q = (ax >= th2) ? 1.5f : q;
        q = (ax >= th3) ? 2.0f : q;
        q = (ax >= th4) ? 3.0f : q;
        q = (ax >= th5) ? 4.0f : q;
        q = (ax >= th6) ? 6.0f : q;
        float xq = q * scale;
        xq = f_asfloat(f_asuint(xq) | (f_asuint(xs[j]) & 0x80000000u));
        af[j] = f2bf(xq);
      }

      acc0 = __builtin_amdgcn_mfma_f32_16x16x32_bf16(af, w8[si][0], acc0, 0, 0, 0);
      acc1 = __builtin_amdgcn_mfma_f32_16x16x32_bf16(af, w8[si][1], acc1, 0, 0, 0);
      acc2 = __builtin_amdgcn_mfma_f32_16x16x32_bf16(af, w8[si][2], acc2, 0, 0, 0);
      acc3 = __builtin_amdgcn_mfma_f32_16x16x32_bf16(af, w8[si][3], acc3, 0, 0, 0);
    }
    __syncthreads();                   // drains next-tile stage, syncs buffers
  }

  // cross-wave reduction of 4 K-split partials -> f32 h2p.
  // red aliases xbuf[0] (all reads of xbuf are complete past the last barrier).
  float* red = &xbuf[0][0];
  float* rw = red + wave * 1024 + (quad * 4) * 64 + tl;
#pragma unroll
  for (int reg = 0; reg < 4; ++reg) {
    rw[reg * 64 + 0]  = acc0[reg];
    rw[reg * 64 + 16] = acc1[reg];
    rw[reg * 64 + 32] = acc2[reg];
    rw[reg * 64 + 48] = acc3[reg];
  }
  __syncthreads();
  {
    const f32x4* r4 = reinterpret_cast<const f32x4*>(red);
    f32x4 v = r4[threadIdx.x];
#pragma unroll
    for (int p = 1; p < 4; ++p) {
      f32x4 u = r4[p * 256 + threadIdx.x];
      v.x += u.x; v.y += u.y; v.z += u.z; v.w += u.w;
    }
    int t = threadIdx.x >> 4;          // token 0..15
    int rr = (threadIdx.x & 15) * 4;   // r offset
    *reinterpret_cast<f32x4*>(h2p + ((size_t)kb * T + t0 + t) * RANK + rr) = v;
  }
}

// ---------------------------------------------------------------------------
// Kernel 2: out[t][m] = bias[m] + h2[t][:] . a_bf[m][:]   (K = 64)
// Prologue sums the 2 f32 K-partials -> bf16 h2 in LDS. Then round-4-verified
// 32t x 256m tile, grid m-fastest, chunked LDS-transpose epilogue, NT stores.
// ---------------------------------------------------------------------------
__global__ __launch_bounds__(256, 4) void k_gemm2(const float* __restrict__ h2p,
                                                  const u16* __restrict__ a_bf,
                                                  const float* __restrict__ bias,
                                                  float* __restrict__ out,
                                                  int T) {
  const int t0 = blockIdx.y * 32;
  const int m0 = blockIdx.x * 256;
  const int wave = threadIdx.x >> 6;
  const int lane = threadIdx.x & 63;
  const int quad = lane >> 4;
  const int tl = lane & 15;

  __shared__ u16 h2l[32 * 72];         // 4608 B, padded stride 72
  __shared__ float tile[16 * 260];     // 16640 B

  // prologue: sum 2 K-partials for this block's 32 tokens, cvt -> bf16 LDS
  {
    int t = threadIdx.x >> 3;            // token 0..31
    int r0 = (threadIdx.x & 7) * 8;      // r offset 0..56
    const float* p = h2p + (size_t)(t0 + t) * RANK + r0;
    f32x4 v0 = *reinterpret_cast<const f32x4*>(p);
    f32x4 v1 = *reinterpret_cast<const f32x4*>(p + 4);
    const float* q = p + (size_t)T * RANK;
    f32x4 u0 = *reinterpret_cast<const f32x4*>(q);
    f32x4 u1 = *reinterpret_cast<const f32x4*>(q + 4);
    v0.x += u0.x; v0.y += u0.y; v0.z += u0.z; v0.w += u0.w;
    v1.x += u1.x; v1.y += u1.y; v1.z += u1.z; v1.w += u1.w;
    s16x8 h;
    h[0] = f2bf(v0.x); h[1] = f2bf(v0.y); h[2] = f2bf(v0.z); h[3] = f2bf(v0.w);
    h[4] = f2bf(v1.x); h[5] = f2bf(v1.y); h[6] = f2bf(v1.z); h[7] = f2bf(v1.w);
    *reinterpret_cast<s16x8*>(h2l + t * 72 + r0) = h;
  }
  __syncthreads();

  const u16* hp0 = h2l + tl * 72 + quad * 8;
  const u16* hp1 = hp0 + 16 * 72;
  const u16* ap = a_bf + (size_t)(m0 + wave * 64 + tl) * RANK + quad * 8;

  f32x4 acc[2][4] = {};

#pragma unroll
  for (int o = 0; o < 64; o += 32) {
    s16x8 a0 = *reinterpret_cast<const s16x8*>(hp0 + o);
    s16x8 a1 = *reinterpret_cast<const s16x8*>(hp1 + o);
#pragma unroll
    for (int mg = 0; mg < 4; ++mg) {
      s16x8 bfr = *reinterpret_cast<const s16x8*>(ap + (size_t)mg * 16 * RANK + o);
      acc[0][mg] = __builtin_amdgcn_mfma_f32_16x16x32_bf16(a0, bfr, acc[0][mg], 0, 0, 0);
      acc[1][mg] = __builtin_amdgcn_mfma_f32_16x16x32_bf16(a1, bfr, acc[1][mg], 0, 0, 0);
    }
  }

#pragma unroll
  for (int tg = 0; tg < 2; ++tg) {
    if (tg) __syncthreads();
#pragma unroll
    for (int mg = 0; mg < 4; ++mg)
#pragma unroll
      for (int reg = 0; reg < 4; ++reg)
        tile[(quad * 4 + reg) * 260 + wave * 64 + mg * 16 + tl] = acc[tg][mg][reg];
    __syncthreads();
#pragma unroll
    for (int i = 0; i < 4; ++i) {
      int idx = threadIdx.x + i * 256;   // 1024 float4 = 16 x 256 chunk
      int row = idx >> 6;
      int c4 = (idx & 63) << 2;
      f32x4 v = *reinterpret_cast<const f32x4*>(tile + row * 260 + c4);
      f32x4 b = *reinterpret_cast<const f32x4*>(bias + m0 + c4);
      f32x4 ov;
      ov.x = v.x + b.x; ov.y = v.y + b.y; ov.z = v.z + b.z; ov.w = v.w + b.w;
      __builtin_nontemporal_store(ov,
        reinterpret_cast<f32x4*>(out + (size_t)(t0 + tg * 16 + row) * N_COLS + m0 + c4));
    }
  }
}

// ---------------------------------------------------------------------------
extern "C" void kernel_launch(void* const* d_in, const int* in_sizes, int n_in,
                              void* d_out, int out_size, void* d_ws, size_t ws_size,
                              hipStream_t stream) {
  const float* x      = (const float*)d_in[0];
  const float* smooth = (const float*)d_in[1];
  const float* a_q    = (const float*)d_in[2];
  const float* b_q    = (const float*)d_in[3];
  const float* c_q_t  = (const float*)d_in[4];
  const float* bias   = (const float*)d_in[5];
  float* out = (float*)d_out;

  const int T = in_sizes[0] / N_COLS;  // 8192 tokens

  u16* W     = (u16*)d_ws;                                  // 512 KB
  u16* a_bf  = (u16*)((char*)d_ws + 524288);                // 512 KB
  float* h2p = (float*)((char*)d_ws + 1048576);             // 2*T*64*4 = 4 MB

  k_prep<<<256, 256, 0, stream>>>(b_q, c_q_t, a_q, W, a_bf);
  dim3 gh(T / 16, 2);
  k_h2<<<gh, 256, 0, stream>>>(x, smooth, W, h2p, T);
  dim3 g2(N_COLS / 256, T / 32);
  k_gemm2<<<g2, 256, 0, stream>>>(h2p, a_bf, bias, out, T);
}